// Round 1
// baseline (494.864 us; speedup 1.0000x reference)
//
#include <hip/hip_runtime.h>

#define S_DIM 20
#define EMB   64
#define MAXP  128   // max peds per scene supported in LDS (actual data: 100)

__global__ __launch_bounds__(256, 4) void pfa_kernel(
    const float* __restrict__ nodes_abs,   // (S,N,2)
    const float* __restrict__ seq_list,    // (S,N)
    const int*   __restrict__ pednum,      // (B)
    const float* __restrict__ W_in,        // (2,EMB)
    const float* __restrict__ W_gm,        // (EMB,EMB)
    const float* __restrict__ b_h,         // (EMB)
    const float* __restrict__ W_out,       // (EMB,2)
    const float* __restrict__ b_out,       // (2)
    float*       __restrict__ out,         // (S,N,2)
    int N, int B)
{
    const int b    = blockIdx.x;
    const int t    = threadIdx.x;
    const int lane = t & 63;
    const int w    = t >> 6;

    __shared__ float gm[MAXP][EMB];          // 32 KB: per-ped gm_sum
    __shared__ float axl[MAXP], ayl[MAXP], mfl[MAXP];
    __shared__ float red[4][3];
    __shared__ int   ired[4];
    __shared__ int   s_start, s_P;

    // ---- scene start offset = exclusive prefix sum of pednum[0..b-1] ----
    {
        int partial = 0;
        for (int i = t; i < b; i += 256) partial += pednum[i];
        #pragma unroll
        for (int off = 32; off > 0; off >>= 1) partial += __shfl_xor(partial, off, 64);
        if (lane == 0) ired[w] = partial;
        __syncthreads();
        if (t == 0) {
            s_start = ired[0] + ired[1] + ired[2] + ired[3];
            s_P     = min(pednum[b], MAXP);
        }
        __syncthreads();
    }
    const int start = s_start;
    const int P     = s_P;

    // ---- zero gm_sum ----
    for (int i = t; i < MAXP * EMB / 4; i += 256)
        ((float4*)gm)[i] = make_float4(0.f, 0.f, 0.f, 0.f);

    // ---- weights in registers: lane j holds column j ----
    float Wcol[EMB];
    #pragma unroll
    for (int k = 0; k < EMB; ++k) Wcol[k] = W_gm[k * EMB + lane];
    const float Win0 = W_in[lane];
    const float Win1 = W_in[EMB + lane];
    const float bh   = b_h[lane];
    const float Wo0  = W_out[lane * 2 + 0];
    const float Wo1  = W_out[lane * 2 + 1];
    const float bo0  = b_out[0], bo1 = b_out[1];

    bool alive = true;                 // thread t owns ped t's running mask
    const int Q = (P + 3) >> 2;        // peds per wave in phase B

    __syncthreads();

    for (int f = 0; f < S_DIM - 1; ++f) {
        // ---------- Phase A: mask update + scene center reduction ----------
        float cnt = 0.f, sx = 0.f, sy = 0.f;
        if (t < P) {
            const int gp = start + t;
            const float pres = seq_list[(size_t)f * N + gp];
            alive = alive && (pres > 0.0f);
            const float mf = alive ? 1.0f : 0.0f;
            const float2 a = *(const float2*)&nodes_abs[((size_t)f * N + gp) * 2];
            mfl[t] = mf; axl[t] = a.x; ayl[t] = a.y;
            cnt = mf; sx = a.x * mf; sy = a.y * mf;
        }
        #pragma unroll
        for (int off = 32; off > 0; off >>= 1) {
            cnt += __shfl_xor(cnt, off, 64);
            sx  += __shfl_xor(sx , off, 64);
            sy  += __shfl_xor(sy , off, 64);
        }
        if (lane == 0) { red[w][0] = cnt; red[w][1] = sx; red[w][2] = sy; }
        __syncthreads();

        const float tc = red[0][0] + red[1][0] + red[2][0] + red[3][0];
        const float tx = red[0][1] + red[1][1] + red[2][1] + red[3][1];
        const float ty = red[0][2] + red[1][2] + red[2][2] + red[3][2];
        const float inv_c = 1.0f / fmaxf(tc, 1.0f);
        const float cx = tx * inv_c, cy = ty * inv_c;
        const float invf = 1.0f / (float)max(f, 1);

        // ---------- Phase B: wave w processes peds [w*Q, min((w+1)*Q,P)) ----------
        const int p0 = w * Q, p1 = min(p0 + Q, P);
        for (int p = p0; p < p1; ++p) {
            const int gp = start + p;
            const size_t oidx = ((size_t)f * N + gp) * 2;
            const float mf = mfl[p];               // wave-uniform broadcast
            if (mf == 0.0f) {
                if (lane == 0) { out[oidx] = 0.0f; out[oidx + 1] = 0.0f; }
                continue;
            }
            // dot_j = sum_k gm[p][k] * W_gm[k][j]
            float dot = 0.0f;
            #pragma unroll
            for (int k = 0; k < EMB; k += 4) {
                const float4 g = *(const float4*)&gm[p][k];   // broadcast b128
                dot = fmaf(g.x, Wcol[k + 0], dot);
                dot = fmaf(g.y, Wcol[k + 1], dot);
                dot = fmaf(g.z, Wcol[k + 2], dot);
                dot = fmaf(g.w, Wcol[k + 3], dot);
            }
            const float pre = fmaf(axl[p] - cx, Win0,
                              fmaf(ayl[p] - cy, Win1,
                              fmaf(dot, invf, bh)));
            // tanh(x) = 1 - 2/(exp(2x)+1)  (safe at +-inf)
            const float e = __expf(2.0f * pre);
            const float h = 1.0f - 2.0f / (e + 1.0f);
            gm[p][lane] += h;                       // conflict-free stride-1 write
            // out = h @ W_out + b_out  (2-wide), butterfly reduce over 64 lanes
            float o0 = h * Wo0, o1 = h * Wo1;
            #pragma unroll
            for (int off = 32; off > 0; off >>= 1) {
                o0 += __shfl_xor(o0, off, 64);
                o1 += __shfl_xor(o1, off, 64);
            }
            if (lane == 0) { out[oidx] = o0 + bo0; out[oidx + 1] = o1 + bo1; }
        }
        __syncthreads();   // protect mfl/axl/red before next step's Phase A
    }

    // ---- final step S-1: zeros ----
    if (t < P) {
        const int gp = start + t;
        const size_t oidx = ((size_t)(S_DIM - 1) * N + gp) * 2;
        out[oidx] = 0.0f; out[oidx + 1] = 0.0f;
    }
}

extern "C" void kernel_launch(void* const* d_in, const int* in_sizes, int n_in,
                              void* d_out, int out_size, void* d_ws, size_t ws_size,
                              hipStream_t stream) {
    const float* nodes_abs = (const float*)d_in[0];
    // d_in[1] nodes_norm, d_in[2] shift_value, d_in[4] scenes: unused by reference
    const float* seq_list  = (const float*)d_in[3];
    const int*   pednum    = (const int*)  d_in[5];
    const float* W_in      = (const float*)d_in[6];
    const float* W_gm      = (const float*)d_in[7];
    const float* b_h       = (const float*)d_in[8];
    const float* W_out     = (const float*)d_in[9];
    const float* b_out     = (const float*)d_in[10];
    float*       out       = (float*)d_out;

    const int N = in_sizes[3] / S_DIM;   // seq_list is (S,N)
    const int B = in_sizes[5];

    pfa_kernel<<<B, 256, 0, stream>>>(nodes_abs, seq_list, pednum,
                                      W_in, W_gm, b_h, W_out, b_out,
                                      out, N, B);
}

// Round 2
// 114.347 us; speedup vs baseline: 4.3277x; 4.3277x over previous
//
#include <hip/hip_runtime.h>

#define S_DIM 20
#define EMB   64
#define MAXP  112   // max peds/scene in LDS (data: 100)
#define GSTR  52    // uint32 words per G row: 48 used (64 gm + 32 aug bf16), pad->52 (208B, 16B-aligned, conflict-free)

typedef __attribute__((ext_vector_type(8))) short bf16x8;
typedef __attribute__((ext_vector_type(4))) float f32x4;

__device__ __forceinline__ uint32_t pk_bf16(float lo, float hi) {
    uint32_t r;
    asm("v_cvt_pk_bf16_f32 %0, %1, %2" : "=v"(r) : "v"(lo), "v"(hi));
    return r;
}
__device__ __forceinline__ short bf16s(float v) {
    return (short)(pk_bf16(v, v) & 0xffffu);
}
__device__ __forceinline__ float unbf16(uint32_t lo16) {
    union { uint32_t u; float f; } c; c.u = lo16 << 16; return c.f;
}

__global__ __launch_bounds__(256, 3) void pfa_kernel(
    const float* __restrict__ nodes_abs,   // (S,N,2)
    const float* __restrict__ seq_list,    // (S,N)
    const int*   __restrict__ pednum,      // (B)
    const float* __restrict__ W_in,        // (2,EMB)
    const float* __restrict__ W_gm,        // (EMB,EMB)
    const float* __restrict__ b_h,         // (EMB)
    const float* __restrict__ W_out,       // (EMB,2)
    const float* __restrict__ b_out,       // (2)
    float*       __restrict__ out,         // (S,N,2)
    int N, int B)
{
    const int b    = blockIdx.x;
    const int t    = threadIdx.x;
    const int lane = t & 63;
    const int l15  = lane & 15;
    const int hi   = lane >> 4;
    const int w    = t >> 6;

    // G row per ped: words 0..31 = 64 bf16 (gm_mean, then reused for h), words 32..47 = aug K-rows, 48..51 pad
    __shared__ uint32_t G[MAXP * GSTR];
    __shared__ float2   axy[MAXP];
    __shared__ float    mfl[MAXP];
    __shared__ float    red[4][3];
    __shared__ int      ired[4];
    __shared__ int      s_start, s_P;

    { // exclusive prefix sum of pednum -> scene start
        int partial = 0;
        for (int i = t; i < b; i += 256) partial += pednum[i];
        #pragma unroll
        for (int off = 32; off > 0; off >>= 1) partial += __shfl_xor(partial, off, 64);
        if (lane == 0) ired[w] = partial;
        __syncthreads();
        if (t == 0) {
            s_start = ired[0] + ired[1] + ired[2] + ired[3];
            s_P     = min(pednum[b], MAXP);
        }
    }

    for (int i = t; i < MAXP * GSTR; i += 256) G[i] = 0;
    for (int i = t; i < MAXP; i += 256) { mfl[i] = 0.0f; axy[i] = make_float2(0.0f, 0.0f); }

    // ---- constant A-fragments (registers) ----
    // pre-MFMA: D[j][ped] = sum_k A[j][k] * Gb[k][ped];  A[j][k] = W_gm[k][j]  (A-frag: row=l15, k=8*hi+e per k-tile)
    bf16x8 agm[4][2];
    #pragma unroll
    for (int m = 0; m < 4; ++m)
        #pragma unroll
        for (int T = 0; T < 2; ++T)
            #pragma unroll
            for (int e = 0; e < 8; ++e)
                agm[m][T][e] = bf16s(W_gm[(32*T + 8*hi + e) * EMB + 16*m + l15]);

    // aug k-tile (k=64..95): rows 64..71 = [w0h,w0l,w0h,w1h,w1l,w1h,bhh,bhl] at column j; rows 72..95 = 0
    bf16x8 aaug[4];
    #pragma unroll
    for (int m = 0; m < 4; ++m) {
        bf16x8 a = {0,0,0,0,0,0,0,0};
        if (hi == 0) {
            const int j = 16*m + l15;
            const float w0 = W_in[j], w1 = W_in[EMB + j], bh = b_h[j];
            const short w0h = bf16s(w0); const short w0l = bf16s(w0 - unbf16((uint16_t)w0h));
            const short w1h = bf16s(w1); const short w1l = bf16s(w1 - unbf16((uint16_t)w1h));
            const short bhh = bf16s(bh); const short bhl = bf16s(bh - unbf16((uint16_t)bhh));
            a[0]=w0h; a[1]=w0l; a[2]=w0h; a[3]=w1h; a[4]=w1l; a[5]=w1h; a[6]=bhh; a[7]=bhl;
        }
        aaug[m] = a;
    }

    // out-MFMA: D2[c][ped] = sum_j Wout[j][c] * H[j][ped]; A2[row=c=l15][k=j]
    bf16x8 aout[2];
    #pragma unroll
    for (int T = 0; T < 2; ++T)
        #pragma unroll
        for (int e = 0; e < 8; ++e) {
            const int j = 32*T + 8*hi + e;
            aout[T][e] = (l15 < 2) ? bf16s(W_out[j*2 + l15]) : (short)0;
        }

    const float bo0 = b_out[0], bo1 = b_out[1];

    __syncthreads();
    const int start = s_start, P = s_P, NRB = (P + 15) >> 4;

    f32x4 gm0[4], gm1[4];
    const f32x4 zero4 = {0.f, 0.f, 0.f, 0.f};
    #pragma unroll
    for (int m = 0; m < 4; ++m) { gm0[m] = zero4; gm1[m] = zero4; }

    bool alive = true;   // thread t owns ped t's running mask (t < P)

    for (int f = 0; f < S_DIM - 1; ++f) {
        // ---------- Phase A: mask update + scene center ----------
        float cnt = 0.f, sx = 0.f, sy = 0.f;
        if (t < P) {
            const int gp = start + t;
            alive = alive && (seq_list[(size_t)f * N + gp] > 0.0f);
            const float mf = alive ? 1.0f : 0.0f;
            const float2 a = *(const float2*)&nodes_abs[((size_t)f * N + gp) * 2];
            mfl[t] = mf; axy[t] = a;
            cnt = mf; sx = a.x * mf; sy = a.y * mf;
        }
        #pragma unroll
        for (int off = 32; off > 0; off >>= 1) {
            cnt += __shfl_xor(cnt, off, 64);
            sx  += __shfl_xor(sx , off, 64);
            sy  += __shfl_xor(sy , off, 64);
        }
        if (lane == 0) { red[w][0] = cnt; red[w][1] = sx; red[w][2] = sy; }
        __syncthreads();

        const float tc = red[0][0] + red[1][0] + red[2][0] + red[3][0];
        const float tx = red[0][1] + red[1][1] + red[2][1] + red[3][1];
        const float ty = red[0][2] + red[1][2] + red[2][2] + red[3][2];
        const float inv_c = 1.0f / fmaxf(tc, 1.0f);
        const float cx = tx * inv_c, cy = ty * inv_c;
        const float invf2 = 1.0f / (float)(f + 1);   // scale for NEXT step's gm_mean

        // ---------- Phase B: one 16-ped row-block per wave per round ----------
        auto do_rb = [&](int rb, f32x4 (&gm)[4]) {
            const int s = rb * 16 + l15;             // ped within scene (this lane's column)
            uint32_t* Grow = &G[s * GSTR];
            const float mf = mfl[s];
            if (hi == 0) {                           // write aug rows k=64..71 (coord hi/lo split + 1)
                const float2 a2 = axy[s];
                const float cxd = a2.x - cx, cyd = a2.y - cy;
                const uint32_t rx = pk_bf16(cxd, cxd);
                const uint32_t ry = pk_bf16(cyd, cyd);
                const float cxl = cxd - unbf16(rx & 0xffffu);
                const float cyl = cyd - unbf16(ry & 0xffffu);
                const uint32_t w33 = pk_bf16(cxl, cyd);
                const uint32_t w34 = pk_bf16(cyd, cyl);
                *(uint2*)&Grow[32] = make_uint2(rx,  w33);
                *(uint2*)&Grow[34] = make_uint2(w34, 0x3f803f80u);
            }
            bf16x8 B0 = *(const bf16x8*)&Grow[ 0 + 4*hi];   // gm_mean k-tile 0
            bf16x8 B1 = *(const bf16x8*)&Grow[16 + 4*hi];   // gm_mean k-tile 1
            bf16x8 B2 = *(const bf16x8*)&Grow[32 + 4*hi];   // aug k-tile
            f32x4 acc[4];
            #pragma unroll
            for (int m = 0; m < 4; ++m) {
                f32x4 c = zero4;
                c = __builtin_amdgcn_mfma_f32_16x16x32_bf16(agm[m][0], B0, c, 0, 0, 0);
                c = __builtin_amdgcn_mfma_f32_16x16x32_bf16(agm[m][1], B1, c, 0, 0, 0);
                c = __builtin_amdgcn_mfma_f32_16x16x32_bf16(aaug[m],   B2, c, 0, 0, 0);
                acc[m] = c;
            }
            const bool live = (mf > 0.0f);
            f32x4 h[4];
            #pragma unroll
            for (int m = 0; m < 4; ++m)
                #pragma unroll
                for (int r = 0; r < 4; ++r) {
                    const float x = acc[m][r];                  // pre-activation, j = 16m+4hi+r
                    const float e = __expf(2.0f * x);
                    const float hv = 1.0f - 2.0f * __builtin_amdgcn_rcpf(e + 1.0f);
                    h[m][r] = live ? hv : 0.0f;
                }
            #pragma unroll
            for (int m = 0; m < 4; ++m) gm[m] += h[m];          // fp32 gm_sum in registers
            // write h (bf16) into words 0..31, read back as B-frags for the out-MFMA
            #pragma unroll
            for (int m = 0; m < 4; ++m) {
                const uint32_t p0 = pk_bf16(h[m][0], h[m][1]);
                const uint32_t p1 = pk_bf16(h[m][2], h[m][3]);
                *(uint2*)&Grow[8*m + 2*hi] = make_uint2(p0, p1);
            }
            bf16x8 H0 = *(const bf16x8*)&Grow[ 0 + 4*hi];
            bf16x8 H1 = *(const bf16x8*)&Grow[16 + 4*hi];
            f32x4 oc = zero4;
            oc = __builtin_amdgcn_mfma_f32_16x16x32_bf16(aout[0], H0, oc, 0, 0, 0);
            oc = __builtin_amdgcn_mfma_f32_16x16x32_bf16(aout[1], H1, oc, 0, 0, 0);
            if (hi == 0 && s < P) {                              // rows c=0,1 live in hi==0, reg 0/1
                const size_t oidx = ((size_t)f * N + (start + s)) * 2;
                float2 o;
                o.x = (oc[0] + bo0) * mf;
                o.y = (oc[1] + bo1) * mf;
                *(float2*)&out[oidx] = o;
            }
            // write next step's gm_mean (bf16) into words 0..31
            #pragma unroll
            for (int m = 0; m < 4; ++m) {
                const uint32_t p0 = pk_bf16(gm[m][0]*invf2, gm[m][1]*invf2);
                const uint32_t p1 = pk_bf16(gm[m][2]*invf2, gm[m][3]*invf2);
                *(uint2*)&Grow[8*m + 2*hi] = make_uint2(p0, p1);
            }
        };

        if (w < NRB)     do_rb(w,     gm0);
        if (w + 4 < NRB) do_rb(w + 4, gm1);

        __syncthreads();   // protect mfl/axy/red for next step's Phase A
    }

    // final step S-1: zeros
    if (t < P) {
        const size_t oidx = ((size_t)(S_DIM - 1) * N + (start + t)) * 2;
        out[oidx] = 0.0f; out[oidx + 1] = 0.0f;
    }
}

extern "C" void kernel_launch(void* const* d_in, const int* in_sizes, int n_in,
                              void* d_out, int out_size, void* d_ws, size_t ws_size,
                              hipStream_t stream) {
    const float* nodes_abs = (const float*)d_in[0];
    const float* seq_list  = (const float*)d_in[3];
    const int*   pednum    = (const int*)  d_in[5];
    const float* W_in      = (const float*)d_in[6];
    const float* W_gm      = (const float*)d_in[7];
    const float* b_h       = (const float*)d_in[8];
    const float* W_out     = (const float*)d_in[9];
    const float* b_out     = (const float*)d_in[10];
    float*       out       = (float*)d_out;

    const int N = in_sizes[3] / S_DIM;
    const int B = in_sizes[5];

    pfa_kernel<<<B, 256, 0, stream>>>(nodes_abs, seq_list, pednum,
                                      W_in, W_gm, b_h, W_out, b_out,
                                      out, N, B);
}

// Round 3
// 100.576 us; speedup vs baseline: 4.9203x; 1.1369x over previous
//
#include <hip/hip_runtime.h>

#define S_DIM 20
#define EMB   64
#define GSTR  36   // uint32 words per ped-row of the per-wave gm buffer (32 used + 4 pad; 13 superbanks -> conflict-free)

typedef __attribute__((ext_vector_type(8))) short bf16x8;
typedef __attribute__((ext_vector_type(4))) float f32x4;

__device__ __forceinline__ uint32_t pk_bf16(float lo, float hi) {
    uint32_t r;
    asm("v_cvt_pk_bf16_f32 %0, %1, %2" : "=v"(r) : "v"(lo), "v"(hi));
    return r;
}
__device__ __forceinline__ short bf16s(float v) {
    return (short)(pk_bf16(v, v) & 0xffffu);
}
__device__ __forceinline__ float unbf16(uint32_t lo16) {
    union { uint32_t u; float f; } c; c.u = lo16 << 16; return c.f;
}

__global__ __launch_bounds__(512, 2) void pfa_kernel(
    const float* __restrict__ nodes_abs,   // (S,N,2)
    const float* __restrict__ seq_list,    // (S,N)
    const int*   __restrict__ pednum,      // (B)
    const float* __restrict__ W_in,        // (2,EMB)
    const float* __restrict__ W_gm,        // (EMB,EMB)
    const float* __restrict__ b_h,         // (EMB)
    const float* __restrict__ W_out,       // (EMB,2)
    const float* __restrict__ b_out,       // (2)
    float*       __restrict__ out,         // (S,N,2)
    int N, int B)
{
    const int b    = blockIdx.x;
    const int t    = threadIdx.x;
    const int lane = t & 63;
    const int w    = t >> 6;
    const int l15  = lane & 15;
    const int hi   = lane >> 4;

    __shared__ uint32_t G[8 * 16 * GSTR];          // 18432 B, wave-private slices
    uint32_t* const Gw = &G[w * 16 * GSTR];

    // ---- per-wave (redundant, barrier-free) scene start: prefix sum of pednum ----
    int partial = 0;
    for (int i = lane; i < b; i += 64) partial += pednum[i];
    #pragma unroll
    for (int off = 32; off; off >>= 1) partial += __shfl_xor(partial, off, 64);
    const int start = partial;
    const int P = min(pednum[b], 128);
    const int q = (P + 7) >> 3;                    // peds per wave (balanced)

    // ---- zero own gm buffer (wave-private; no barrier needed) ----
    for (int i = lane; i < 16 * GSTR; i += 64) Gw[i] = 0;

    // ---- constant fragments ----
    // pre-MFMA: D[j][ped] = sum_k W_gm[k][j] * gm_mean[k][ped];  A-frag: row j=16m+l15, k=32T+8hi+e
    bf16x8 agm[4][2];
    #pragma unroll
    for (int m = 0; m < 4; ++m)
        #pragma unroll
        for (int T = 0; T < 2; ++T)
            #pragma unroll
            for (int e = 0; e < 8; ++e)
                agm[m][T][e] = bf16s(W_gm[(32*T + 8*hi + e) * EMB + 16*m + l15]);

    // aug A-tile: k rows 0..7 (abs 64..71) = [w0h,w0l,w0h,w1h,w1l,w1h,bhh,bhl] for column j; rows 8..31 zero
    bf16x8 aaug[4];
    #pragma unroll
    for (int m = 0; m < 4; ++m) {
        bf16x8 a = {0,0,0,0,0,0,0,0};
        if (hi == 0) {
            const int j = 16*m + l15;
            const float w0 = W_in[j], w1 = W_in[EMB + j], bh = b_h[j];
            const short w0h = bf16s(w0); const short w0l = bf16s(w0 - unbf16((uint16_t)w0h));
            const short w1h = bf16s(w1); const short w1l = bf16s(w1 - unbf16((uint16_t)w1h));
            const short bhh = bf16s(bh); const short bhl = bf16s(bh - unbf16((uint16_t)bhh));
            a[0]=w0h; a[1]=w0l; a[2]=w0h; a[3]=w1h; a[4]=w1l; a[5]=w1h; a[6]=bhh; a[7]=bhl;
        }
        aaug[m] = a;
    }

    // W_out in C-layout registers: j = 16m+4hi+r
    f32x4 wo0[4], wo1[4];
    #pragma unroll
    for (int m = 0; m < 4; ++m)
        #pragma unroll
        for (int r = 0; r < 4; ++r) {
            const float2 v = *(const float2*)&W_out[(16*m + 4*hi + r) * 2];
            wo0[m][r] = v.x; wo1[m][r] = v.y;
        }
    const float bo0 = b_out[0], bo1 = b_out[1];

    // ---- ped assignments ----
    const int  pA = lane, pB = lane + 64, pR = w * q + l15;
    const bool vA = pA < P, vB = pB < P;
    const bool vR = (l15 < q) && (pR < P);
    const int  iA = start + (vA ? pA : 0);
    const int  iB = start + (vB ? pB : 0);
    const int  iR = start + (vR ? pR : 0);

    // step-0 values
    float  seqA = seq_list[iA], seqB = seq_list[iB], seqR = seq_list[iR];
    float2 absA = *(const float2*)&nodes_abs[(size_t)iA * 2];
    float2 absB = *(const float2*)&nodes_abs[(size_t)iB * 2];
    float2 absR = *(const float2*)&nodes_abs[(size_t)iR * 2];

    bool aliveA = true, aliveB = true, aliveR = true;
    f32x4 gm[4];
    const f32x4 zero4 = {0.f, 0.f, 0.f, 0.f};
    #pragma unroll
    for (int m = 0; m < 4; ++m) gm[m] = zero4;

    #pragma unroll 1
    for (int f = 0; f < S_DIM - 1; ++f) {
        // ---- mask update + local partial sums ----
        aliveA = aliveA && (seqA > 0.0f);
        aliveB = aliveB && (seqB > 0.0f);
        aliveR = aliveR && (seqR > 0.0f);
        const float mfA = (aliveA && vA) ? 1.0f : 0.0f;
        const float mfB = (aliveB && vB) ? 1.0f : 0.0f;
        const float mfR = (aliveR && vR) ? 1.0f : 0.0f;
        float cnt = mfA + mfB;
        float sx  = fmaf(absA.x, mfA, absB.x * mfB);
        float sy  = fmaf(absA.y, mfA, absB.y * mfB);
        const float axR = absR.x, ayR = absR.y;

        // ---- prefetch next step's inputs (hides under reduce+MFMA) ----
        const size_t nb = (size_t)(f + 1) * N;
        const float  nseqA = seq_list[nb + iA], nseqB = seq_list[nb + iB], nseqR = seq_list[nb + iR];
        const float2 nabsA = *(const float2*)&nodes_abs[(nb + iA) * 2];
        const float2 nabsB = *(const float2*)&nodes_abs[(nb + iB) * 2];
        const float2 nabsR = *(const float2*)&nodes_abs[(nb + iR) * 2];

        // ---- wave-wide reduce (center) ----
        #pragma unroll
        for (int off = 32; off; off >>= 1) {
            cnt += __shfl_xor(cnt, off, 64);
            sx  += __shfl_xor(sx , off, 64);
            sy  += __shfl_xor(sy , off, 64);
        }
        const float inv_c = __builtin_amdgcn_rcpf(fmaxf(cnt, 1.0f));
        const float cx = sx * inv_c, cy = sy * inv_c;
        const float cxd = axR - cx, cyd = ayR - cy;

        // ---- aug B-fragment in registers (hi==0 rows only) ----
        const uint32_t e0 = pk_bf16(cxd, cxd);
        const float    cxl = cxd - unbf16(e0 & 0xffffu);
        const uint32_t ey = pk_bf16(cyd, cyd);
        const float    cyl = cyd - unbf16(ey & 0xffffu);
        const uint32_t e1 = pk_bf16(cxl, cyd);
        const uint32_t e2 = pk_bf16(cyd, cyl);
        union { uint32_t u[4]; bf16x8 v; } b2u;
        const bool h0 = (hi == 0);
        b2u.u[0] = h0 ? e0 : 0u;
        b2u.u[1] = h0 ? e1 : 0u;
        b2u.u[2] = h0 ? e2 : 0u;
        b2u.u[3] = h0 ? 0x3f803f80u : 0u;

        // ---- gm_mean B-fragments from wave-private LDS ----
        const bf16x8 B0 = *(const bf16x8*)&Gw[l15 * GSTR +      4*hi];
        const bf16x8 B1 = *(const bf16x8*)&Gw[l15 * GSTR + 16 + 4*hi];

        f32x4 acc[4];
        #pragma unroll
        for (int m = 0; m < 4; ++m) {
            f32x4 c = zero4;
            c = __builtin_amdgcn_mfma_f32_16x16x32_bf16(aaug[m],   b2u.v, c, 0, 0, 0);
            c = __builtin_amdgcn_mfma_f32_16x16x32_bf16(agm[m][0], B0,    c, 0, 0, 0);
            c = __builtin_amdgcn_mfma_f32_16x16x32_bf16(agm[m][1], B1,    c, 0, 0, 0);
            acc[m] = c;
        }

        // ---- tanh + gm accumulate + out dot ----
        const float m2 = -2.0f * mfR;
        float o0 = 0.0f, o1 = 0.0f;
        f32x4 h[4];
        #pragma unroll
        for (int m = 0; m < 4; ++m) {
            #pragma unroll
            for (int r = 0; r < 4; ++r) {
                const float x  = acc[m][r];
                const float e  = __expf(2.0f * x);
                const float tt = __builtin_amdgcn_rcpf(e + 1.0f);
                const float hv = fmaf(tt, m2, mfR);       // mf * (1 - 2/(e+1))
                h[m][r] = hv;
                o0 = fmaf(hv, wo0[m][r], o0);
                o1 = fmaf(hv, wo1[m][r], o1);
            }
            gm[m] += h[m];
        }
        o0 += __shfl_xor(o0, 16, 64);  o0 += __shfl_xor(o0, 32, 64);
        o1 += __shfl_xor(o1, 16, 64);  o1 += __shfl_xor(o1, 32, 64);
        if (h0 && vR) {
            float2 o;
            o.x = (o0 + bo0) * mfR;
            o.y = (o1 + bo1) * mfR;
            *(float2*)&out[((size_t)f * N + iR) * 2] = o;
        }

        // ---- write next step's gm_mean (bf16) into wave-private LDS ----
        const float invf2 = __builtin_amdgcn_rcpf((float)(f + 1));
        #pragma unroll
        for (int m = 0; m < 4; ++m) {
            const uint32_t p0 = pk_bf16(gm[m][0] * invf2, gm[m][1] * invf2);
            const uint32_t p1 = pk_bf16(gm[m][2] * invf2, gm[m][3] * invf2);
            *(uint2*)&Gw[l15 * GSTR + 8*m + 2*hi] = make_uint2(p0, p1);
        }

        // rotate prefetched values
        seqA = nseqA; seqB = nseqB; seqR = nseqR;
        absA = nabsA; absB = nabsB; absR = nabsR;
    }

    // ---- final step S-1: zeros ----
    if (t < P) {
        const size_t o = ((size_t)(S_DIM - 1) * N + start + t) * 2;
        out[o] = 0.0f; out[o + 1] = 0.0f;
    }
}

extern "C" void kernel_launch(void* const* d_in, const int* in_sizes, int n_in,
                              void* d_out, int out_size, void* d_ws, size_t ws_size,
                              hipStream_t stream) {
    const float* nodes_abs = (const float*)d_in[0];
    const float* seq_list  = (const float*)d_in[3];
    const int*   pednum    = (const int*)  d_in[5];
    const float* W_in      = (const float*)d_in[6];
    const float* W_gm      = (const float*)d_in[7];
    const float* b_h       = (const float*)d_in[8];
    const float* W_out     = (const float*)d_in[9];
    const float* b_out     = (const float*)d_in[10];
    float*       out       = (float*)d_out;

    const int N = in_sizes[3] / S_DIM;
    const int B = in_sizes[5];

    pfa_kernel<<<B, 512, 0, stream>>>(nodes_abs, seq_list, pednum,
                                      W_in, W_gm, b_h, W_out, b_out,
                                      out, N, B);
}